// Round 6
// baseline (5265.585 us; speedup 1.0000x reference)
//
#include <hip/hip_runtime.h>
#include <hip/hip_bf16.h>

typedef __hip_bfloat16 bf16;

#define N_FEA   3145728   // 2*96*128*128
#define N_EN    196608    // 2*96*32*32
#define N_E1    786432    // 2*96*64*64
#define OUT_EN  3145728
#define OUT_Q   3342336

__device__ __forceinline__ float b2f(bf16 v) { return __bfloat162float(v); }
template <typename T> __device__ __forceinline__ void stv(T* p, long i, float v);
template <> __device__ __forceinline__ void stv<float>(float* p, long i, float v) { p[i] = v; }
template <> __device__ __forceinline__ void stv<bf16>(bf16* p, long i, float v) {
    p[i] = __float2bfloat16(v);
}

// Direct 3x3 conv, pad=1, stride S, PX outputs/thread, virtual concat (in0:c0,in1:c1).
// Block = (b, oc, strip of 256*PX px); weights for oc staged in LDS.
template <int S, int PX, typename OT>
__global__ __launch_bounds__(256) void conv3x3_v2(
    const float* __restrict__ in0, int c0,
    const float* __restrict__ in1, int c1,
    const float* __restrict__ w, const float* __restrict__ bias,
    const float* __restrict__ addsrc,   // if non-null: out = addsrc + act(conv)
    OT* __restrict__ out,
    int Cout, int Hin, int Win, int relu) {
    const int Hout = (Hin - 1) / S + 1, Wout = (Win - 1) / S + 1;
    const int strips = (Hout * Wout) / (256 * PX);
    int bid = blockIdx.x;
    const int strip = bid % strips; bid /= strips;
    const int oc = bid % Cout;
    const int b = bid / Cout;
    const int Cin = c0 + c1;
    __shared__ float wl[1728];          // up to 192 ch * 9
    for (int i = threadIdx.x; i < Cin * 9; i += 256)
        wl[i] = w[(long)oc * Cin * 9 + i];
    __syncthreads();
    const int pix = strip * 256 * PX + threadIdx.x * PX;
    const int oy = pix / Wout, oxb = pix % Wout;
    const int iy0 = oy * S - 1, ixb = oxb * S - 1;
    constexpr int NX = (PX - 1) * S + 3;
    float acc[PX];
    const float bz = bias[oc];
#pragma unroll
    for (int j = 0; j < PX; ++j) acc[j] = bz;
    const bool fast = (ixb >= 0) && (ixb + NX - 1 < Win);

    auto seg = [&](const float* base, int nc, int wofs) {
        const float* pl = base + (long)b * nc * Hin * Win;
        for (int c = 0; c < nc; ++c) {
            float wv[9];
#pragma unroll
            for (int k = 0; k < 9; ++k) wv[k] = wl[(wofs + c) * 9 + k];
#pragma unroll
            for (int ky = 0; ky < 3; ++ky) {
                int iy = iy0 + ky;
                if ((unsigned)iy >= (unsigned)Hin) continue;
                const float* row = pl + (long)iy * Win + ixb;
                float r[NX];
                if (fast) {
#pragma unroll
                    for (int i = 0; i < NX; ++i) r[i] = row[i];
                } else {
#pragma unroll
                    for (int i = 0; i < NX; ++i) {
                        int col = ixb + i;
                        r[i] = ((unsigned)col < (unsigned)Win) ? row[i] : 0.f;
                    }
                }
#pragma unroll
                for (int j = 0; j < PX; ++j)
#pragma unroll
                    for (int kx = 0; kx < 3; ++kx)
                        acc[j] = fmaf(r[j * S + kx], wv[ky * 3 + kx], acc[j]);
            }
            pl += (long)Hin * Win;
        }
    };
    seg(in0, c0, 0);
    seg(in1, c1, c0);

    long idx = (((long)b * Cout + oc) * Hout + oy) * Wout + oxb;
#pragma unroll
    for (int j = 0; j < PX; ++j) {
        float a = acc[j];
        if (relu) a = a > 0.f ? a : 0.1f * a;
        if (addsrc) a += addsrc[idx + j];
        stv<OT>(out, idx + j, a);
    }
}

// ConvTranspose2d(96->96,k3,s2,p1,op1), gather form, 4 ox per thread (oxb even).
__global__ __launch_bounds__(256) void convt3x3_v2(
    const float* __restrict__ in, const float* __restrict__ w,
    const float* __restrict__ bias, float* __restrict__ out,
    int Hin, int Win, int relu) {
    const int C = 96;
    const int Hout = 2 * Hin, Wout = 2 * Win;
    const int strips = (Hout * Wout) / 1024;
    int bid = blockIdx.x;
    const int strip = bid % strips; bid /= strips;
    const int oc = bid % C;
    const int b = bid / C;
    __shared__ float wl[864];
    for (int i = threadIdx.x; i < C * 9; i += 256) {
        int c = i / 9, k = i % 9;
        wl[i] = w[((long)c * C + oc) * 9 + k];
    }
    __syncthreads();
    const int pix = strip * 1024 + threadIdx.x * 4;
    const int oy = pix / Wout, oxb = pix % Wout;
    const int c0x = oxb >> 1;
    const int oyE = oy + 1;
    float acc[4];
    const float bz = bias[oc];
#pragma unroll
    for (int j = 0; j < 4; ++j) acc[j] = bz;
    const bool r2ok = (c0x + 2) < Win;

    const float* pl = in + (long)b * C * Hin * Win;
    for (int c = 0; c < C; ++c) {
        float wv[9];
#pragma unroll
        for (int k = 0; k < 9; ++k) wv[k] = wl[c * 9 + k];
#pragma unroll
        for (int ky = 0; ky < 3; ++ky) {
            int ty = oyE - ky;
            if (ty & 1) continue;
            int iy = ty >> 1;
            if ((unsigned)iy >= (unsigned)Hin) continue;
            const float* row = pl + (long)iy * Win + c0x;
            float r0 = row[0];
            float r1 = row[1];
            float r2 = r2ok ? row[2] : 0.f;
            acc[0] = fmaf(r0, wv[ky * 3 + 1], acc[0]);
            acc[1] = fmaf(r1, wv[ky * 3 + 0], acc[1]);
            acc[1] = fmaf(r0, wv[ky * 3 + 2], acc[1]);
            acc[2] = fmaf(r1, wv[ky * 3 + 1], acc[2]);
            acc[3] = fmaf(r2, wv[ky * 3 + 0], acc[3]);
            acc[3] = fmaf(r1, wv[ky * 3 + 2], acc[3]);
        }
        pl += (long)Hin * Win;
    }
    long idx = (((long)b * C + oc) * Hout + oy) * Wout + oxb;
#pragma unroll
    for (int j = 0; j < 4; ++j) {
        float a = acc[j];
        if (relu) a = a > 0.f ? a : 0.1f * a;
        out[idx + j] = a;
    }
}

__global__ void quant_k(const float* __restrict__ en, float* __restrict__ out_en,
                        float* __restrict__ out_q, float* __restrict__ qf, int n) {
    int i = blockIdx.x * 256 + threadIdx.x;
    if (i >= n) return;
    float e = en[i];
    float q = rintf(e);
    out_en[i] = e;
    out_q[i] = q;
    qf[i] = q;
}

// DCNv1 sample+contract, offsets precomputed (bf16 [b][144][H][W]).
// Block = (b, oy, 4 px); LDS 16.1 KB -> ~9 blocks/CU.
__global__ __launch_bounds__(128) void deform_lite_k(
    const float* __restrict__ x, const bf16* __restrict__ offs,
    const float* __restrict__ dw, const float* __restrict__ db,
    float* __restrict__ out) {
    const int H = 128, W = 128, C = 96, TX = 4;
    __shared__ float offL[TX][144];
    __shared__ float s[TX][864];
    int bid = blockIdx.x;
    int oxb = (bid % (W / TX)) * TX; bid /= (W / TX);
    int oy = bid % H;
    int b = bid / H;
    int tid = threadIdx.x;
    for (int e = tid; e < TX * 144; e += 128) {
        int p = e / 144, cc = e % 144;
        offL[p][cc] = b2f(offs[(((long)b * 144 + cc) * H + oy) * W + oxb + p]);
    }
    __syncthreads();
    for (int e = tid; e < TX * 864; e += 128) {
        int p = e / 864, r = e % 864;
        int c = r / 9, kk = r % 9, g = c / 12;
        int ox = oxb + p;
        float offy = offL[p][g * 18 + kk * 2];
        float offx = offL[p][g * 18 + kk * 2 + 1];
        float py = (float)(oy + kk / 3 - 1) + offy;
        float px = (float)(ox + kk % 3 - 1) + offx;
        float y0f = floorf(py), x0f = floorf(px);
        float ly = py - y0f, lx = px - x0f;
        int y0 = (int)y0f, x0 = (int)x0f;
        const float* pl = x + ((long)b * C + c) * (long)H * W;
        float w00 = (1.f - ly) * (1.f - lx), w01 = (1.f - ly) * lx;
        float w10 = ly * (1.f - lx), w11 = ly * lx;
        float v = 0.f;
        if ((unsigned)y0 < (unsigned)H && (unsigned)x0 < (unsigned)W)
            v = fmaf(pl[y0 * W + x0], w00, v);
        if ((unsigned)y0 < (unsigned)H && (unsigned)(x0 + 1) < (unsigned)W)
            v = fmaf(pl[y0 * W + x0 + 1], w01, v);
        if ((unsigned)(y0 + 1) < (unsigned)H && (unsigned)x0 < (unsigned)W)
            v = fmaf(pl[(y0 + 1) * W + x0], w10, v);
        if ((unsigned)(y0 + 1) < (unsigned)H && (unsigned)(x0 + 1) < (unsigned)W)
            v = fmaf(pl[(y0 + 1) * W + x0 + 1], w11, v);
        s[p][c * 9 + kk] = v;
    }
    __syncthreads();
    if (tid < C) {
        int oc = tid;
        float bz = db[oc];
        float a0 = bz, a1 = bz, a2 = bz, a3 = bz;
        const float* wp = dw + (long)oc * 864;
        for (int i = 0; i < 864; ++i) {
            float wv = wp[i];
            a0 = fmaf(s[0][i], wv, a0);
            a1 = fmaf(s[1][i], wv, a1);
            a2 = fmaf(s[2][i], wv, a2);
            a3 = fmaf(s[3][i], wv, a3);
        }
        long ob = (((long)b * C + oc) * H + oy) * W + oxb;
        out[ob + 0] = a0; out[ob + 1] = a1; out[ob + 2] = a2; out[ob + 3] = a3;
    }
}

// Fallback: fused offset-conv + DCNv1 (one-slot workspace mode).
__global__ __launch_bounds__(128) void deform_fused_k(
    const float* __restrict__ x, const float* __restrict__ de,
    const float* __restrict__ cw, const float* __restrict__ cb,
    const float* __restrict__ dw, const float* __restrict__ db,
    float* __restrict__ out) {
    const int H = 128, W = 128, C = 96, TX = 4;
    __shared__ float deL[96 * 18];
    __shared__ float offL[TX][144];
    __shared__ float s[TX][864];
    int bid = blockIdx.x;
    int oxb = (bid % (W / TX)) * TX; bid /= (W / TX);
    int oy = bid % H;
    int b = bid / H;
    int tid = threadIdx.x;
    for (int e = tid; e < 96 * 18; e += 128) {
        int c = e / 18, r = e % 18, ry = r / 6, cx = r % 6;
        int iy = oy - 1 + ry, ix = oxb - 1 + cx;
        float v = 0.f;
        if ((unsigned)iy < (unsigned)H && (unsigned)ix < (unsigned)W)
            v = de[((long)(b * C + c) * H + iy) * W + ix];
        deL[e] = v;
    }
    __syncthreads();
    for (int cc = tid; cc < 144; cc += 128) {
        float bz = cb[cc];
        float a0 = bz, a1 = bz, a2 = bz, a3 = bz;
        const float* wr = cw + (long)cc * C * 9;
        for (int c = 0; c < C; ++c) {
            const float* dl = deL + c * 18;
#pragma unroll
            for (int ky = 0; ky < 3; ++ky)
#pragma unroll
                for (int kx = 0; kx < 3; ++kx) {
                    float wv = wr[c * 9 + ky * 3 + kx];
                    const float* dr = dl + ky * 6 + kx;
                    a0 = fmaf(dr[0], wv, a0);
                    a1 = fmaf(dr[1], wv, a1);
                    a2 = fmaf(dr[2], wv, a2);
                    a3 = fmaf(dr[3], wv, a3);
                }
        }
        offL[0][cc] = a0; offL[1][cc] = a1; offL[2][cc] = a2; offL[3][cc] = a3;
    }
    __syncthreads();
    for (int e = tid; e < TX * 864; e += 128) {
        int p = e / 864, r = e % 864;
        int c = r / 9, kk = r % 9, g = c / 12;
        int ox = oxb + p;
        float offy = offL[p][g * 18 + kk * 2];
        float offx = offL[p][g * 18 + kk * 2 + 1];
        float py = (float)(oy + kk / 3 - 1) + offy;
        float px = (float)(ox + kk % 3 - 1) + offx;
        float y0f = floorf(py), x0f = floorf(px);
        float ly = py - y0f, lx = px - x0f;
        int y0 = (int)y0f, x0 = (int)x0f;
        const float* pl = x + ((long)b * C + c) * (long)H * W;
        float w00 = (1.f - ly) * (1.f - lx), w01 = (1.f - ly) * lx;
        float w10 = ly * (1.f - lx), w11 = ly * lx;
        float v = 0.f;
        if ((unsigned)y0 < (unsigned)H && (unsigned)x0 < (unsigned)W)
            v = fmaf(pl[y0 * W + x0], w00, v);
        if ((unsigned)y0 < (unsigned)H && (unsigned)(x0 + 1) < (unsigned)W)
            v = fmaf(pl[y0 * W + x0 + 1], w01, v);
        if ((unsigned)(y0 + 1) < (unsigned)H && (unsigned)x0 < (unsigned)W)
            v = fmaf(pl[(y0 + 1) * W + x0], w10, v);
        if ((unsigned)(y0 + 1) < (unsigned)H && (unsigned)(x0 + 1) < (unsigned)W)
            v = fmaf(pl[(y0 + 1) * W + x0 + 1], w11, v);
        s[p][c * 9 + kk] = v;
    }
    __syncthreads();
    if (tid < C) {
        int oc = tid;
        float bz = db[oc];
        float a0 = bz, a1 = bz, a2 = bz, a3 = bz;
        const float* wp = dw + (long)oc * 864;
        for (int i = 0; i < 864; ++i) {
            float wv = wp[i];
            a0 = fmaf(s[0][i], wv, a0);
            a1 = fmaf(s[1][i], wv, a1);
            a2 = fmaf(s[2][i], wv, a2);
            a3 = fmaf(s[3][i], wv, a3);
        }
        long ob = (((long)b * C + oc) * H + oy) * W + oxb;
        out[ob + 0] = a0; out[ob + 1] = a1; out[ob + 2] = a2; out[ob + 3] = a3;
    }
}

extern "C" void kernel_launch(void* const* d_in, const int* in_sizes, int n_in,
                              void* d_out, int out_size, void* d_ws, size_t ws_size,
                              hipStream_t stream) {
    const float* ref_fea = (const float*)d_in[0];
    const float* inp_fea = (const float*)d_in[1];
    const float* oc1_w = (const float*)d_in[2];  const float* oc1_b = (const float*)d_in[3];
    const float* oc3_w = (const float*)d_in[4];  const float* oc3_b = (const float*)d_in[5];
    const float* enc1_w = (const float*)d_in[6]; const float* enc1_b = (const float*)d_in[7];
    const float* enc2_w = (const float*)d_in[8]; const float* enc2_b = (const float*)d_in[9];
    const float* dec1_w = (const float*)d_in[10]; const float* dec1_b = (const float*)d_in[11];
    const float* dec2_w = (const float*)d_in[12]; const float* dec2_b = (const float*)d_in[13];
    const float* coff_w = (const float*)d_in[14]; const float* coff_b = (const float*)d_in[15];
    const float* dcn_w = (const float*)d_in[16];  const float* dcn_b = (const float*)d_in[17];
    const float* ref1_w = (const float*)d_in[18]; const float* ref1_b = (const float*)d_in[19];
    const float* ref2_w = (const float*)d_in[20]; const float* ref2_b = (const float*)d_in[21];

    float* out = (float*)d_out;
    float* S1 = (float*)d_ws;
    bool two_slots = ws_size >= (size_t)2 * N_FEA * sizeof(float);
    float* S2 = two_slots ? (S1 + N_FEA) : out;   // out0 region as 2nd slot if needed
    float* E = S1 + N_E1;
    float* F = E + N_EN;

    dim3 blk(256);
    dim3 g_f8(2 * 96 * 8);     // 128x128 out, PX=8
    dim3 g_h4(2 * 96 * 4);     // 64x64 out, PX=4 (convT strips)
    dim3 g_e1(2 * 96 * 2);     // 64x64 out, conv PX=4 strips=2... (4096/1024=4) -> fix below

    // 1. t1 = lrelu(conv(cat(ref,inp), oc1)) -> S1
    conv3x3_v2<1, 8, float><<<g_f8, blk, 0, stream>>>(ref_fea, 96, inp_fea, 96,
                                                      oc1_w, oc1_b, nullptr, S1,
                                                      96, 128, 128, 1);
    // 2. t2 = lrelu(conv(t1, oc3)) -> S2
    conv3x3_v2<1, 8, float><<<g_f8, blk, 0, stream>>>(S1, 96, S1, 0, oc3_w, oc3_b,
                                                      nullptr, S2, 96, 128, 128, 1);
    // 3. e1 = lrelu(conv_s2(t2, enc1)) -> S1[0..N_E1)   (64x64: strips = 4096/1024 = 4)
    conv3x3_v2<2, 4, float><<<dim3(2 * 96 * 4), blk, 0, stream>>>(S2, 96, S2, 0,
                                                                  enc1_w, enc1_b, nullptr,
                                                                  S1, 96, 128, 128, 1);
    // 4. en = conv_s2(e1, enc2) -> E   (32x32: strips = 1024/1024 = 1)
    conv3x3_v2<2, 4, float><<<dim3(2 * 96), blk, 0, stream>>>(S1, 96, S1, 0,
                                                              enc2_w, enc2_b, nullptr,
                                                              E, 96, 64, 64, 0);
    // 5. outputs 1/2 + q fp32 -> F
    quant_k<<<dim3((N_EN + 255) / 256), blk, 0, stream>>>(E, out + OUT_EN, out + OUT_Q,
                                                          F, N_EN);
    // 6. d1 = lrelu(convT(q, dec1)) -> S2[0..N_E1)
    convt3x3_v2<<<g_h4, blk, 0, stream>>>(F, dec1_w, dec1_b, S2, 32, 32, 1);
    // 7. de = convT(d1, dec2) -> S1
    convt3x3_v2<<<dim3(2 * 96 * 16), blk, 0, stream>>>(S2, dec2_w, dec2_b, S1, 64, 64, 0);

    if (two_slots) {
        // 8a. offsets = conv(de, coff) -> bf16 in S2   (144 ch, strips = 16384/2048 = 8)
        bf16* offsB = (bf16*)S2;
        conv3x3_v2<1, 8, bf16><<<dim3(2 * 144 * 8), blk, 0, stream>>>(S1, 96, S1, 0,
                                                                      coff_w, coff_b, nullptr,
                                                                      offsB, 144, 128, 128, 0);
        // 8b. aligned = deform(ref_fea, offs) -> S1 (de dead)
        deform_lite_k<<<dim3(2 * 128 * 32), dim3(128), 0, stream>>>(ref_fea, offsB,
                                                                    dcn_w, dcn_b, S1);
        // 9. r1 = lrelu(conv(cat(aligned, ref_fea), ref1)) -> S2 (offsets dead)
        conv3x3_v2<1, 8, float><<<g_f8, blk, 0, stream>>>(S1, 96, ref_fea, 96,
                                                          ref1_w, ref1_b, nullptr, S2,
                                                          96, 128, 128, 1);
        // 10. out0 = aligned + lrelu(conv(r1, ref2))
        conv3x3_v2<1, 8, float><<<g_f8, blk, 0, stream>>>(S2, 96, S2, 0, ref2_w, ref2_b,
                                                          S1, out, 96, 128, 128, 1);
    } else {
        // One-slot fallback: fused deform; aligned lives in out region (S2 == out).
        deform_fused_k<<<dim3(2 * 128 * 32), dim3(128), 0, stream>>>(ref_fea, S1,
                                                                     coff_w, coff_b,
                                                                     dcn_w, dcn_b, S2);
        conv3x3_v2<1, 8, float><<<g_f8, blk, 0, stream>>>(S2, 96, ref_fea, 96,
                                                          ref1_w, ref1_b, nullptr, S1,
                                                          96, 128, 128, 1);
        conv3x3_v2<1, 8, float><<<g_f8, blk, 0, stream>>>(S1, 96, S1, 0, ref2_w, ref2_b,
                                                          S2, out, 96, 128, 128, 1);
    }
}

// Round 7
// 2163.606 us; speedup vs baseline: 2.4337x; 2.4337x over previous
//
#include <hip/hip_runtime.h>
#include <hip/hip_bf16.h>

typedef __hip_bfloat16 bf16;
typedef __attribute__((ext_vector_type(8))) short s8;   // 8 x bf16 MFMA A/B frag
typedef __attribute__((ext_vector_type(4))) float f4;   // MFMA C/D frag

#define N_FEA   3145728   // 2*96*128*128
#define N_EN    196608    // 2*96*32*32
#define N_E1    786432    // 2*96*64*64
#define OUT_EN  3145728
#define OUT_Q   3342336

__device__ __forceinline__ float b2f(bf16 v) { return __bfloat162float(v); }

// ---------------- scalar direct conv (round-5 proven shape, PX=4, + OCB) --------------
template <int S, int OCB>
__global__ __launch_bounds__(256) void conv3x3_v2(
    const float* __restrict__ in0, int c0,
    const float* __restrict__ in1, int c1,
    const float* __restrict__ w, const float* __restrict__ bias,
    float* __restrict__ out,
    int Cout, int Hin, int Win, int relu) {
    const int Hout = (Hin - 1) / S + 1, Wout = (Win - 1) / S + 1;
    const int strips = (Hout * Wout) / 1024;
    int bid = blockIdx.x;
    const int strip = bid % strips; bid /= strips;
    const int oc0 = (bid % (Cout / OCB)) * OCB;
    const int b = bid / (Cout / OCB);
    const int Cin = c0 + c1;
    __shared__ float wl[OCB * 1728];
    for (int i = threadIdx.x; i < OCB * Cin * 9; i += 256) {
        int o = i / (Cin * 9), rem = i % (Cin * 9);
        wl[i] = w[(long)(oc0 + o) * Cin * 9 + rem];
    }
    __syncthreads();
    const int pix = strip * 1024 + threadIdx.x * 4;
    const int oy = pix / Wout, oxb = pix % Wout;
    const int iy0 = oy * S - 1, ixb = oxb * S - 1;
    constexpr int NX = 3 * S + 3;
    float acc[OCB][4];
    const float bz0 = bias[oc0];
    const float bz1 = (OCB > 1) ? bias[oc0 + OCB - 1] : 0.f;
#pragma unroll
    for (int o = 0; o < OCB; ++o)
#pragma unroll
        for (int j = 0; j < 4; ++j) acc[o][j] = (o == 0) ? bz0 : bz1;
    const bool fast = (ixb >= 0) && (ixb + NX - 1 < Win);

    auto seg = [&](const float* base, int nc, int wofs) {
        const float* pl = base + (long)b * nc * Hin * Win;
        for (int c = 0; c < nc; ++c) {
#pragma unroll
            for (int ky = 0; ky < 3; ++ky) {
                int iy = iy0 + ky;
                if ((unsigned)iy >= (unsigned)Hin) continue;
                const float* row = pl + (long)iy * Win + ixb;
                float r[NX];
                if (fast) {
#pragma unroll
                    for (int i = 0; i < NX; ++i) r[i] = row[i];
                } else {
#pragma unroll
                    for (int i = 0; i < NX; ++i) {
                        int col = ixb + i;
                        r[i] = ((unsigned)col < (unsigned)Win) ? row[i] : 0.f;
                    }
                }
#pragma unroll
                for (int o = 0; o < OCB; ++o) {
                    const float* wv = &wl[(o * Cin + wofs + c) * 9 + ky * 3];
#pragma unroll
                    for (int j = 0; j < 4; ++j)
#pragma unroll
                        for (int kx = 0; kx < 3; ++kx)
                            acc[o][j] = fmaf(r[j * S + kx], wv[kx], acc[o][j]);
                }
            }
            pl += (long)Hin * Win;
        }
    };
    seg(in0, c0, 0);
    seg(in1, c1, c0);

#pragma unroll
    for (int o = 0; o < OCB; ++o) {
        long idx = (((long)b * Cout + oc0 + o) * Hout + oy) * Wout + oxb;
#pragma unroll
        for (int j = 0; j < 4; ++j) {
            float a = acc[o][j];
            if (relu) a = a > 0.f ? a : 0.1f * a;
            out[idx + j] = a;
        }
    }
}

// ------------- ConvTranspose2d(96->96,k3,s2,p1,op1), gather, 4 ox/thread --------------
// HWC=0: fp32 NCHW out. HWC=1: bf16 HWC out [b][y][x][96].
template <int HWC>
__global__ __launch_bounds__(256) void convt3x3_v2(
    const float* __restrict__ in, const float* __restrict__ w,
    const float* __restrict__ bias, void* __restrict__ out,
    int Hin, int Win, int relu) {
    const int C = 96;
    const int Hout = 2 * Hin, Wout = 2 * Win;
    const int strips = (Hout * Wout) / 1024;
    int bid = blockIdx.x;
    const int strip = bid % strips; bid /= strips;
    const int oc = bid % C;
    const int b = bid / C;
    __shared__ float wl[864];
    for (int i = threadIdx.x; i < C * 9; i += 256) {
        int c = i / 9, k = i % 9;
        wl[i] = w[((long)c * C + oc) * 9 + k];
    }
    __syncthreads();
    const int pix = strip * 1024 + threadIdx.x * 4;
    const int oy = pix / Wout, oxb = pix % Wout;
    const int c0x = oxb >> 1;
    const int oyE = oy + 1;
    float acc[4];
    const float bz = bias[oc];
#pragma unroll
    for (int j = 0; j < 4; ++j) acc[j] = bz;
    const bool r2ok = (c0x + 2) < Win;

    const float* pl = in + (long)b * C * Hin * Win;
    for (int c = 0; c < C; ++c) {
        float wv[9];
#pragma unroll
        for (int k = 0; k < 9; ++k) wv[k] = wl[c * 9 + k];
#pragma unroll
        for (int ky = 0; ky < 3; ++ky) {
            int ty = oyE - ky;
            if (ty & 1) continue;
            int iy = ty >> 1;
            if ((unsigned)iy >= (unsigned)Hin) continue;
            const float* row = pl + (long)iy * Win + c0x;
            float r0 = row[0];
            float r1 = row[1];
            float r2 = r2ok ? row[2] : 0.f;
            acc[0] = fmaf(r0, wv[ky * 3 + 1], acc[0]);
            acc[1] = fmaf(r1, wv[ky * 3 + 0], acc[1]);
            acc[1] = fmaf(r0, wv[ky * 3 + 2], acc[1]);
            acc[2] = fmaf(r1, wv[ky * 3 + 1], acc[2]);
            acc[3] = fmaf(r2, wv[ky * 3 + 0], acc[3]);
            acc[3] = fmaf(r1, wv[ky * 3 + 2], acc[3]);
        }
        pl += (long)Hin * Win;
    }
#pragma unroll
    for (int j = 0; j < 4; ++j) {
        float a = acc[j];
        if (relu) a = a > 0.f ? a : 0.1f * a;
        if (HWC)
            ((bf16*)out)[((long)b * Hout * Wout + oy * Wout + oxb + j) * 96 + oc] =
                __float2bfloat16(a);
        else
            ((float*)out)[(((long)b * C + oc) * Hout + oy) * Wout + oxb + j] = a;
    }
}

__global__ void quant_k(const float* __restrict__ en, float* __restrict__ out_en,
                        float* __restrict__ out_q, float* __restrict__ qf, int n) {
    int i = blockIdx.x * 256 + threadIdx.x;
    if (i >= n) return;
    float e = en[i];
    float q = rintf(e);
    out_en[i] = e;
    out_q[i] = q;
    qf[i] = q;
}

// -------- weight transform: w fp32 [Cout][Cin][3][3] -> wT bf16 [Cout][9][Cin] --------
// swap=1 permutes channels by +Cin/2 mod Cin (for ref1's concat reorder).
__global__ void wxform(const float* __restrict__ w, bf16* __restrict__ wT,
                       int Cout, int Cin, int swap) {
    long tot = (long)Cout * 9 * Cin;
    long i = (long)blockIdx.x * 256 + threadIdx.x;
    if (i >= tot) return;
    int c = (int)(i % Cin);
    long t = i / Cin;
    int tap = (int)(t % 9);
    int oc = (int)(t / 9);
    int cs = swap ? (c + Cin / 2) % Cin : c;
    wT[i] = __float2bfloat16(w[((long)oc * Cin + cs) * 9 + tap]);
}

// -------- pack fp32 NCHW (96 ch) -> bf16 HWC [b][y][x][Cs] at channel offset --------
__global__ void pack_hwc(const float* __restrict__ src, bf16* __restrict__ dst,
                         int HW, int Cs, int coff) {
    long i = (long)blockIdx.x * 256 + threadIdx.x;
    if (i >= 2L * 96 * HW) return;
    int px = (int)(i % HW);
    long t = i / HW;
    int c = (int)(t % 96);
    int b = (int)(t / 96);
    dst[((long)b * HW + px) * Cs + coff + c] = __float2bfloat16(src[i]);
}

// ----------------- MFMA implicit-GEMM 3x3 conv (stride 1, 128x128) -----------------
// X: bf16 HWC [b][H][W][Cin]; wT: bf16 [Cout][9][Cin]; K-order = tap*Cin + c.
// Block 256 thr = 4 waves: wave covers 32 px (2 m-tiles) x half the oc-groups.
// EPI 0: bf16 HWC out (Cs=Cout). EPI 2: bf16 NCHW. EPI 3: fp32 NCHW + residual
// from res (192-c HWC, channels 96..191).
template <int EPI>
__global__ __launch_bounds__(256) void mconv(
    const bf16* __restrict__ X, const bf16* __restrict__ wT,
    const float* __restrict__ bias, void* __restrict__ out,
    const bf16* __restrict__ res,
    int Cin, int Cout, int H, int W, int relu) {
    const int HW = H * W;
    const int NG = Cout >> 4, split = (NG + 1) >> 1;
    int bid = blockIdx.x;
    const int nb = HW >> 6;
    const int pxb = (bid % nb) << 6;
    const int b = bid / nb;
    const int wave = threadIdx.x >> 6, lane = threadIdx.x & 63;
    const int mt = (wave >> 1) << 5;            // +0 / +32 px
    const int og0 = (wave & 1) ? split : 0;
    const int og1 = (wave & 1) ? NG : split;
    const int q = lane >> 4, n16 = lane & 15;
    const int pA0 = pxb + mt + n16, pA1 = pA0 + 16;
    const int oy0 = pA0 / W, ox0 = pA0 % W;
    const int oy1 = pA1 / W, ox1 = pA1 % W;
    const long ib = (long)b * HW * Cin;
    f4 acc0[5], acc1[5];
    const f4 z4 = {0.f, 0.f, 0.f, 0.f};
#pragma unroll
    for (int g = 0; g < 5; ++g) { acc0[g] = z4; acc1[g] = z4; }
    const s8 z8 = {0, 0, 0, 0, 0, 0, 0, 0};
    const int cpt = Cin >> 5;                   // 32-wide K chunks per tap
    for (int tap = 0; tap < 9; ++tap) {
        const int ky = tap / 3 - 1, kx = tap % 3 - 1;
        const int iy0 = oy0 + ky, ix0 = ox0 + kx;
        const int iy1 = oy1 + ky, ix1 = ox1 + kx;
        const bool v0 = (unsigned)iy0 < (unsigned)H && (unsigned)ix0 < (unsigned)W;
        const bool v1 = (unsigned)iy1 < (unsigned)H && (unsigned)ix1 < (unsigned)W;
        const bf16* pa0 = X + ib + ((long)iy0 * W + ix0) * Cin + q * 8;
        const bf16* pa1 = X + ib + ((long)iy1 * W + ix1) * Cin + q * 8;
        const bf16* pb = wT + ((long)n16 * 9 + tap) * Cin + q * 8;
        for (int ci = 0; ci < cpt; ++ci) {
            const int c0 = ci << 5;
            s8 a0 = v0 ? *(const s8*)(pa0 + c0) : z8;
            s8 a1 = v1 ? *(const s8*)(pa1 + c0) : z8;
#pragma unroll
            for (int gi = 0; gi < 5; ++gi) {
                int g = og0 + gi;
                if (g >= og1) break;
                s8 bb = *(const s8*)(pb + (long)g * 144 * Cin + c0);   // 16*9=144
                acc0[gi] = __builtin_amdgcn_mfma_f32_16x16x32_bf16(a0, bb, acc0[gi], 0, 0, 0);
                acc1[gi] = __builtin_amdgcn_mfma_f32_16x16x32_bf16(a1, bb, acc1[gi], 0, 0, 0);
            }
        }
    }
#pragma unroll
    for (int gi = 0; gi < 5; ++gi) {
        int g = og0 + gi;
        if (g >= og1) break;
        int oc = g * 16 + n16;
        float bz = bias[oc];
#pragma unroll
        for (int t = 0; t < 2; ++t) {
            f4 a = t ? acc1[gi] : acc0[gi];
            int pxl = pxb + mt + t * 16 + q * 4;   // D row = q*4 + reg
#pragma unroll
            for (int r = 0; r < 4; ++r) {
                float v = a[r] + bz;
                if (relu) v = v > 0.f ? v : 0.1f * v;
                int px = pxl + r;
                if (EPI == 0)
                    ((bf16*)out)[((long)b * HW + px) * Cout + oc] = __float2bfloat16(v);
                else if (EPI == 2)
                    ((bf16*)out)[((long)b * Cout + oc) * HW + px] = __float2bfloat16(v);
                else {
                    v += b2f(res[((long)b * HW + px) * 192 + 96 + oc]);
                    ((float*)out)[((long)b * Cout + oc) * HW + px] = v;
                }
            }
        }
    }
}

// ---------------- DCNv1 sample+contract; writes aligned into X2 HWC (c 96..191) ------
__global__ __launch_bounds__(128) void deform_lite_k(
    const float* __restrict__ x, const bf16* __restrict__ offs,
    const float* __restrict__ dw, const float* __restrict__ db,
    bf16* __restrict__ X2) {
    const int H = 128, W = 128, C = 96, TX = 4;
    __shared__ float offL[TX][144];
    __shared__ float s[TX][864];
    int bid = blockIdx.x;
    int oxb = (bid % (W / TX)) * TX; bid /= (W / TX);
    int oy = bid % H;
    int b = bid / H;
    int tid = threadIdx.x;
    for (int e = tid; e < TX * 144; e += 128) {
        int p = e / 144, cc = e % 144;
        offL[p][cc] = b2f(offs[(((long)b * 144 + cc) * H + oy) * W + oxb + p]);
    }
    __syncthreads();
    for (int e = tid; e < TX * 864; e += 128) {
        int p = e / 864, r = e % 864;
        int c = r / 9, kk = r % 9, g = c / 12;
        int ox = oxb + p;
        float offy = offL[p][g * 18 + kk * 2];
        float offx = offL[p][g * 18 + kk * 2 + 1];
        float py = (float)(oy + kk / 3 - 1) + offy;
        float px = (float)(ox + kk % 3 - 1) + offx;
        float y0f = floorf(py), x0f = floorf(px);
        float ly = py - y0f, lx = px - x0f;
        int y0 = (int)y0f, x0 = (int)x0f;
        const float* pl = x + ((long)b * C + c) * (long)H * W;
        float w00 = (1.f - ly) * (1.f - lx), w01 = (1.f - ly) * lx;
        float w10 = ly * (1.f - lx), w11 = ly * lx;
        float v = 0.f;
        if ((unsigned)y0 < (unsigned)H && (unsigned)x0 < (unsigned)W)
            v = fmaf(pl[y0 * W + x0], w00, v);
        if ((unsigned)y0 < (unsigned)H && (unsigned)(x0 + 1) < (unsigned)W)
            v = fmaf(pl[y0 * W + x0 + 1], w01, v);
        if ((unsigned)(y0 + 1) < (unsigned)H && (unsigned)x0 < (unsigned)W)
            v = fmaf(pl[(y0 + 1) * W + x0], w10, v);
        if ((unsigned)(y0 + 1) < (unsigned)H && (unsigned)(x0 + 1) < (unsigned)W)
            v = fmaf(pl[(y0 + 1) * W + x0 + 1], w11, v);
        s[p][c * 9 + kk] = v;
    }
    __syncthreads();
    if (tid < C) {
        int oc = tid;
        float bz = db[oc];
        float a0 = bz, a1 = bz, a2 = bz, a3 = bz;
        const float* wp = dw + (long)oc * 864;
        for (int i = 0; i < 864; ++i) {
            float wv = wp[i];
            a0 = fmaf(s[0][i], wv, a0);
            a1 = fmaf(s[1][i], wv, a1);
            a2 = fmaf(s[2][i], wv, a2);
            a3 = fmaf(s[3][i], wv, a3);
        }
        long ob = ((long)b * 16384 + oy * 128 + oxb) * 192 + 96 + oc;
        X2[ob + 0 * 192] = __float2bfloat16(a0);
        X2[ob + 1 * 192] = __float2bfloat16(a1);
        X2[ob + 2 * 192] = __float2bfloat16(a2);
        X2[ob + 3 * 192] = __float2bfloat16(a3);
    }
}

extern "C" void kernel_launch(void* const* d_in, const int* in_sizes, int n_in,
                              void* d_out, int out_size, void* d_ws, size_t ws_size,
                              hipStream_t stream) {
    const float* ref_fea = (const float*)d_in[0];
    const float* inp_fea = (const float*)d_in[1];
    const float* oc1_w = (const float*)d_in[2];  const float* oc1_b = (const float*)d_in[3];
    const float* oc3_w = (const float*)d_in[4];  const float* oc3_b = (const float*)d_in[5];
    const float* enc1_w = (const float*)d_in[6]; const float* enc1_b = (const float*)d_in[7];
    const float* enc2_w = (const float*)d_in[8]; const float* enc2_b = (const float*)d_in[9];
    const float* dec1_w = (const float*)d_in[10]; const float* dec1_b = (const float*)d_in[11];
    const float* dec2_w = (const float*)d_in[12]; const float* dec2_b = (const float*)d_in[13];
    const float* coff_w = (const float*)d_in[14]; const float* coff_b = (const float*)d_in[15];
    const float* dcn_w = (const float*)d_in[16];  const float* dcn_b = (const float*)d_in[17];
    const float* ref1_w = (const float*)d_in[18]; const float* ref1_b = (const float*)d_in[19];
    const float* ref2_w = (const float*)d_in[20]; const float* ref2_b = (const float*)d_in[21];

    float* out = (float*)d_out;
    float* S1 = (float*)d_ws;             // 12.58 MB slot
    float* S2 = S1 + N_FEA;               // 12.58 MB slot (ws >= 25.2 MB verified r6)
    float* E = S1 + N_E1;                 // en fp32
    float* F = E + N_EN;                  // q fp32
    bf16* de_hwc = (bf16*)S1;             // after F is dead
    bf16* offs = (bf16*)S2;               // 9.44 MB, after d1 dead
    bf16* X2 = (bf16*)S1;                 // 12.58 MB [ref | aligned] HWC 192c
    bf16* r1 = (bf16*)S2;                 // 6.29 MB, after offs dead
    bf16* wtb = (bf16*)S2 + 4800000;      // 0.75 MB at S2+9.6MB (safe tail)
    bf16* wt_coff = wtb;                  // 144*9*96  = 124416
    bf16* wt_ref1 = wt_coff + 124416;     // 96*9*192  = 165888
    bf16* wt_ref2 = wt_ref1 + 165888;     // 96*9*96   = 82944

    dim3 blk(256);
    auto nb = [](long n) { return dim3((unsigned)((n + 255) / 256)); };

    // ---- encoder (fp32-exact; q must match reference round()) ----
    conv3x3_v2<1, 2><<<dim3(2 * 48 * 16), blk, 0, stream>>>(ref_fea, 96, inp_fea, 96,
                                                            oc1_w, oc1_b, S1, 96, 128, 128, 1);
    conv3x3_v2<1, 2><<<dim3(2 * 48 * 16), blk, 0, stream>>>(S1, 96, S1, 0,
                                                            oc3_w, oc3_b, S2, 96, 128, 128, 1);
    conv3x3_v2<2, 1><<<dim3(2 * 96 * 4), blk, 0, stream>>>(S2, 96, S2, 0,
                                                           enc1_w, enc1_b, S1, 96, 128, 128, 1);
    // S2 tail free from here: weight transforms for the MFMA convs
    wxform<<<nb(144L * 9 * 96), blk, 0, stream>>>(coff_w, wt_coff, 144, 96, 0);
    wxform<<<nb(96L * 9 * 192), blk, 0, stream>>>(ref1_w, wt_ref1, 96, 192, 1);
    wxform<<<nb(96L * 9 * 96), blk, 0, stream>>>(ref2_w, wt_ref2, 96, 96, 0);
    conv3x3_v2<2, 1><<<dim3(2 * 96), blk, 0, stream>>>(S1, 96, S1, 0,
                                                       enc2_w, enc2_b, E, 96, 64, 64, 0);
    quant_k<<<nb(N_EN), blk, 0, stream>>>(E, out + OUT_EN, out + OUT_Q, F, N_EN);
    // ---- decoder ----
    convt3x3_v2<0><<<dim3(2 * 96 * 4), blk, 0, stream>>>(F, dec1_w, dec1_b, S2, 32, 32, 1);
    convt3x3_v2<1><<<dim3(2 * 96 * 16), blk, 0, stream>>>(S2, dec2_w, dec2_b, de_hwc,
                                                          64, 64, 0);
    // ---- MFMA: offsets = conv(de) ----
    mconv<2><<<dim3(512), blk, 0, stream>>>(de_hwc, wt_coff, coff_b, offs, nullptr,
                                            96, 144, 128, 128, 0);
    // ---- X2 = [ref | aligned] HWC ----
    pack_hwc<<<nb(N_FEA), blk, 0, stream>>>(ref_fea, X2, 16384, 192, 0);
    deform_lite_k<<<dim3(2 * 128 * 32), dim3(128), 0, stream>>>(ref_fea, offs,
                                                                dcn_w, dcn_b, X2);
    // ---- MFMA: r1 = lrelu(conv(X2, ref1)); out0 = aligned + lrelu(conv(r1, ref2)) ----
    mconv<0><<<dim3(512), blk, 0, stream>>>(X2, wt_ref1, ref1_b, r1, nullptr,
                                            192, 96, 128, 128, 1);
    mconv<3><<<dim3(512), blk, 0, stream>>>(r1, wt_ref2, ref2_b, out, X2,
                                            96, 96, 128, 128, 1);
}

// Round 8
// 1717.951 us; speedup vs baseline: 3.0650x; 1.2594x over previous
//
#include <hip/hip_runtime.h>
#include <hip/hip_bf16.h>

typedef __hip_bfloat16 bf16;
typedef __attribute__((ext_vector_type(8))) short s8;   // 8 x bf16 MFMA A/B frag
typedef __attribute__((ext_vector_type(4))) float f4;   // MFMA C/D frag

#define N_FEA   3145728   // 2*96*128*128
#define N_EN    196608    // 2*96*32*32
#define N_E1    786432    // 2*96*64*64
#define OUT_EN  3145728
#define OUT_Q   3342336

__device__ __forceinline__ float b2f(bf16 v) { return __bfloat162float(v); }

// ---------------- scalar direct conv (PX=4, OCB oc per block) --------------
template <int S, int OCB>
__global__ __launch_bounds__(256) void conv3x3_v2(
    const float* __restrict__ in0, int c0,
    const float* __restrict__ in1, int c1,
    const float* __restrict__ w, const float* __restrict__ bias,
    float* __restrict__ out,
    int Cout, int Hin, int Win, int relu) {
    const int Hout = (Hin - 1) / S + 1, Wout = (Win - 1) / S + 1;
    const int strips = (Hout * Wout) / 1024;
    int bid = blockIdx.x;
    const int strip = bid % strips; bid /= strips;
    const int oc0 = (bid % (Cout / OCB)) * OCB;
    const int b = bid / (Cout / OCB);
    const int Cin = c0 + c1;
    __shared__ float wl[OCB * 1728];
    for (int i = threadIdx.x; i < OCB * Cin * 9; i += 256) {
        int o = i / (Cin * 9), rem = i % (Cin * 9);
        wl[i] = w[(long)(oc0 + o) * Cin * 9 + rem];
    }
    __syncthreads();
    const int pix = strip * 1024 + threadIdx.x * 4;
    const int oy = pix / Wout, oxb = pix % Wout;
    const int iy0 = oy * S - 1, ixb = oxb * S - 1;
    constexpr int NX = 3 * S + 3;
    float acc[OCB][4];
    const float bz0 = bias[oc0];
    const float bz1 = (OCB > 1) ? bias[oc0 + OCB - 1] : 0.f;
#pragma unroll
    for (int o = 0; o < OCB; ++o)
#pragma unroll
        for (int j = 0; j < 4; ++j) acc[o][j] = (o == 0) ? bz0 : bz1;
    const bool fast = (ixb >= 0) && (ixb + NX - 1 < Win);

    auto seg = [&](const float* base, int nc, int wofs) {
        const float* pl = base + (long)b * nc * Hin * Win;
        for (int c = 0; c < nc; ++c) {
#pragma unroll
            for (int ky = 0; ky < 3; ++ky) {
                int iy = iy0 + ky;
                if ((unsigned)iy >= (unsigned)Hin) continue;
                const float* row = pl + (long)iy * Win + ixb;
                float r[NX];
                if (fast) {
#pragma unroll
                    for (int i = 0; i < NX; ++i) r[i] = row[i];
                } else {
#pragma unroll
                    for (int i = 0; i < NX; ++i) {
                        int col = ixb + i;
                        r[i] = ((unsigned)col < (unsigned)Win) ? row[i] : 0.f;
                    }
                }
#pragma unroll
                for (int o = 0; o < OCB; ++o) {
                    const float* wv = &wl[(o * Cin + wofs + c) * 9 + ky * 3];
#pragma unroll
                    for (int j = 0; j < 4; ++j)
#pragma unroll
                        for (int kx = 0; kx < 3; ++kx)
                            acc[o][j] = fmaf(r[j * S + kx], wv[kx], acc[o][j]);
                }
            }
            pl += (long)Hin * Win;
        }
    };
    seg(in0, c0, 0);
    seg(in1, c1, c0);

#pragma unroll
    for (int o = 0; o < OCB; ++o) {
        long idx = (((long)b * Cout + oc0 + o) * Hout + oy) * Wout + oxb;
#pragma unroll
        for (int j = 0; j < 4; ++j) {
            float a = acc[o][j];
            if (relu) a = a > 0.f ? a : 0.1f * a;
            out[idx + j] = a;
        }
    }
}

// ------------- ConvTranspose2d(96->96,k3,s2,p1,op1), gather, 4 ox/thread --------------
template <int HWC>
__global__ __launch_bounds__(256) void convt3x3_v2(
    const float* __restrict__ in, const float* __restrict__ w,
    const float* __restrict__ bias, void* __restrict__ out,
    int Hin, int Win, int relu) {
    const int C = 96;
    const int Hout = 2 * Hin, Wout = 2 * Win;
    const int strips = (Hout * Wout) / 1024;
    int bid = blockIdx.x;
    const int strip = bid % strips; bid /= strips;
    const int oc = bid % C;
    const int b = bid / C;
    __shared__ float wl[864];
    for (int i = threadIdx.x; i < C * 9; i += 256) {
        int c = i / 9, k = i % 9;
        wl[i] = w[((long)c * C + oc) * 9 + k];
    }
    __syncthreads();
    const int pix = strip * 1024 + threadIdx.x * 4;
    const int oy = pix / Wout, oxb = pix % Wout;
    const int c0x = oxb >> 1;
    const int oyE = oy + 1;
    float acc[4];
    const float bz = bias[oc];
#pragma unroll
    for (int j = 0; j < 4; ++j) acc[j] = bz;
    const bool r2ok = (c0x + 2) < Win;

    const float* pl = in + (long)b * C * Hin * Win;
    for (int c = 0; c < C; ++c) {
        float wv[9];
#pragma unroll
        for (int k = 0; k < 9; ++k) wv[k] = wl[c * 9 + k];
#pragma unroll
        for (int ky = 0; ky < 3; ++ky) {
            int ty = oyE - ky;
            if (ty & 1) continue;
            int iy = ty >> 1;
            if ((unsigned)iy >= (unsigned)Hin) continue;
            const float* row = pl + (long)iy * Win + c0x;
            float r0 = row[0];
            float r1 = row[1];
            float r2 = r2ok ? row[2] : 0.f;
            acc[0] = fmaf(r0, wv[ky * 3 + 1], acc[0]);
            acc[1] = fmaf(r1, wv[ky * 3 + 0], acc[1]);
            acc[1] = fmaf(r0, wv[ky * 3 + 2], acc[1]);
            acc[2] = fmaf(r1, wv[ky * 3 + 1], acc[2]);
            acc[3] = fmaf(r2, wv[ky * 3 + 0], acc[3]);
            acc[3] = fmaf(r1, wv[ky * 3 + 2], acc[3]);
        }
        pl += (long)Hin * Win;
    }
#pragma unroll
    for (int j = 0; j < 4; ++j) {
        float a = acc[j];
        if (relu) a = a > 0.f ? a : 0.1f * a;
        if (HWC)
            ((bf16*)out)[((long)b * Hout * Wout + oy * Wout + oxb + j) * 96 + oc] =
                __float2bfloat16(a);
        else
            ((float*)out)[(((long)b * C + oc) * Hout + oy) * Wout + oxb + j] = a;
    }
}

__global__ void quant_k(const float* __restrict__ en, float* __restrict__ out_en,
                        float* __restrict__ out_q, float* __restrict__ qf, int n) {
    int i = blockIdx.x * 256 + threadIdx.x;
    if (i >= n) return;
    float e = en[i];
    float q = rintf(e);
    out_en[i] = e;
    out_q[i] = q;
    qf[i] = q;
}

// -------- weight transform: fp32 [Cout][Cin][3][3] -> bf16 [Cout][9][Cin] --------
__global__ void wxform(const float* __restrict__ w, bf16* __restrict__ wT,
                       int Cout, int Cin, int swap) {
    long tot = (long)Cout * 9 * Cin;
    long i = (long)blockIdx.x * 256 + threadIdx.x;
    if (i >= tot) return;
    int c = (int)(i % Cin);
    long t = i / Cin;
    int tap = (int)(t % 9);
    int oc = (int)(t / 9);
    int cs = swap ? (c + Cin / 2) % Cin : c;
    wT[i] = __float2bfloat16(w[((long)oc * Cin + cs) * 9 + tap]);
}

// -------- dcn_w fp32 [oc][864] -> fp32 [864][oc] (coalesced per-lane oc reads) --------
__global__ void wxform_dcn(const float* __restrict__ w, float* __restrict__ wT) {
    int i = blockIdx.x * 256 + threadIdx.x;
    if (i >= 864 * 96) return;
    int oc = i % 96, k = i / 96;
    wT[i] = w[(long)oc * 864 + k];
}

// -------- pack fp32 NCHW (96 ch) -> bf16 HWC [b][y][x][Cs] at channel offset --------
__global__ void pack_hwc(const float* __restrict__ src, bf16* __restrict__ dst,
                         int HW, int Cs, int coff) {
    long i = (long)blockIdx.x * 256 + threadIdx.x;
    if (i >= 2L * 96 * HW) return;
    int px = (int)(i % HW);
    long t = i / HW;
    int c = (int)(t % 96);
    int b = (int)(t / 96);
    dst[((long)b * HW + px) * Cs + coff + c] = __float2bfloat16(src[i]);
}

// ----------------- MFMA implicit-GEMM 3x3 conv (stride 1, 128x128) -----------------
// X: bf16 HWC; wT: bf16 [Cout][9][Cin]. EPI 0: bf16 HWC out. EPI 3: fp32 NCHW +
// residual from res (192c HWC, channels 96..191).
template <int EPI>
__global__ __launch_bounds__(256) void mconv(
    const bf16* __restrict__ X, const bf16* __restrict__ wT,
    const float* __restrict__ bias, void* __restrict__ out,
    const bf16* __restrict__ res,
    int Cin, int Cout, int H, int W, int relu) {
    const int HW = H * W;
    const int NG = Cout >> 4, split = (NG + 1) >> 1;
    int bid = blockIdx.x;
    const int nb = HW >> 6;
    const int pxb = (bid % nb) << 6;
    const int b = bid / nb;
    const int wave = threadIdx.x >> 6, lane = threadIdx.x & 63;
    const int mt = (wave >> 1) << 5;
    const int og0 = (wave & 1) ? split : 0;
    const int og1 = (wave & 1) ? NG : split;
    const int q = lane >> 4, n16 = lane & 15;
    const int pA0 = pxb + mt + n16, pA1 = pA0 + 16;
    const int oy0 = pA0 / W, ox0 = pA0 % W;
    const int oy1 = pA1 / W, ox1 = pA1 % W;
    const long ib = (long)b * HW * Cin;
    f4 acc0[5], acc1[5];
    const f4 z4 = {0.f, 0.f, 0.f, 0.f};
#pragma unroll
    for (int g = 0; g < 5; ++g) { acc0[g] = z4; acc1[g] = z4; }
    const s8 z8 = {0, 0, 0, 0, 0, 0, 0, 0};
    const int cpt = Cin >> 5;
    for (int tap = 0; tap < 9; ++tap) {
        const int ky = tap / 3 - 1, kx = tap % 3 - 1;
        const int iy0 = oy0 + ky, ix0 = ox0 + kx;
        const int iy1 = oy1 + ky, ix1 = ox1 + kx;
        const bool v0 = (unsigned)iy0 < (unsigned)H && (unsigned)ix0 < (unsigned)W;
        const bool v1 = (unsigned)iy1 < (unsigned)H && (unsigned)ix1 < (unsigned)W;
        const bf16* pa0 = X + ib + ((long)iy0 * W + ix0) * Cin + q * 8;
        const bf16* pa1 = X + ib + ((long)iy1 * W + ix1) * Cin + q * 8;
        const bf16* pb = wT + ((long)n16 * 9 + tap) * Cin + q * 8;
        for (int ci = 0; ci < cpt; ++ci) {
            const int c0 = ci << 5;
            s8 a0 = v0 ? *(const s8*)(pa0 + c0) : z8;
            s8 a1 = v1 ? *(const s8*)(pa1 + c0) : z8;
#pragma unroll
            for (int gi = 0; gi < 5; ++gi) {
                int g = og0 + gi;
                if (g >= og1) break;
                s8 bb = *(const s8*)(pb + (long)g * 144 * Cin + c0);
                acc0[gi] = __builtin_amdgcn_mfma_f32_16x16x32_bf16(a0, bb, acc0[gi], 0, 0, 0);
                acc1[gi] = __builtin_amdgcn_mfma_f32_16x16x32_bf16(a1, bb, acc1[gi], 0, 0, 0);
            }
        }
    }
#pragma unroll
    for (int gi = 0; gi < 5; ++gi) {
        int g = og0 + gi;
        if (g >= og1) break;
        int oc = g * 16 + n16;
        float bz = bias[oc];
#pragma unroll
        for (int t = 0; t < 2; ++t) {
            f4 a = t ? acc1[gi] : acc0[gi];
            int pxl = pxb + mt + t * 16 + q * 4;
#pragma unroll
            for (int r = 0; r < 4; ++r) {
                float v = a[r] + bz;
                if (relu) v = v > 0.f ? v : 0.1f * v;
                int px = pxl + r;
                if (EPI == 0)
                    ((bf16*)out)[((long)b * HW + px) * Cout + oc] = __float2bfloat16(v);
                else {
                    v += b2f(res[((long)b * HW + px) * 192 + 96 + oc]);
                    ((float*)out)[((long)b * Cout + oc) * HW + px] = v;
                }
            }
        }
    }
}

// -------- DCNv1 sample+contract. offs bf16 HWC [b][HW][144]; dwT fp32 [864][96].
// XCD-banded decode: residue r = bid&7 owns rows [16r,16r+16) (L2 locality).
// LDS 9.2 KB -> 16 blocks/CU. Writes aligned into X2 HWC (c 96..191). --------
__global__ __launch_bounds__(128) void deform_lite_k(
    const float* __restrict__ x, const bf16* __restrict__ offs,
    const float* __restrict__ dwT, const float* __restrict__ db,
    bf16* __restrict__ X2) {
    const int H = 128, W = 128, C = 96;
    __shared__ float offL[4][144];
    __shared__ bf16 s[4][864];
    int bid = blockIdx.x;
    int rxcd = bid & 7;
    int i0 = bid >> 3;
    int b = i0 >> 9;
    int rem = i0 & 511;
    int oy = rxcd * 16 + (rem >> 5);
    int oxb = (rem & 31) << 2;
    int tid = threadIdx.x;
    long pxbase = (long)b * (H * W) + oy * W + oxb;
    for (int e = tid; e < 4 * 144; e += 128) {
        int p = e / 144, cc = e % 144;                 // lanes -> consecutive cc: coalesced
        offL[p][cc] = b2f(offs[(pxbase + p) * 144 + cc]);
    }
    __syncthreads();
    for (int e = tid; e < 4 * 864; e += 128) {
        int p = e & 3;                                  // px fastest: line sharing
        int t = e >> 2;
        int kk = t % 9, c = t / 9, g = c / 12;
        int ox = oxb + p;
        float offy = offL[p][g * 18 + kk * 2];
        float offx = offL[p][g * 18 + kk * 2 + 1];
        float py = (float)(oy + kk / 3 - 1) + offy;
        float px = (float)(ox + kk % 3 - 1) + offx;
        float y0f = floorf(py), x0f = floorf(px);
        float ly = py - y0f, lx = px - x0f;
        int y0 = (int)y0f, x0 = (int)x0f;
        const float* pl = x + ((long)b * C + c) * (long)H * W;
        float w00 = (1.f - ly) * (1.f - lx), w01 = (1.f - ly) * lx;
        float w10 = ly * (1.f - lx), w11 = ly * lx;
        float v = 0.f;
        if ((unsigned)y0 < (unsigned)H && (unsigned)x0 < (unsigned)W)
            v = fmaf(pl[y0 * W + x0], w00, v);
        if ((unsigned)y0 < (unsigned)H && (unsigned)(x0 + 1) < (unsigned)W)
            v = fmaf(pl[y0 * W + x0 + 1], w01, v);
        if ((unsigned)(y0 + 1) < (unsigned)H && (unsigned)x0 < (unsigned)W)
            v = fmaf(pl[(y0 + 1) * W + x0], w10, v);
        if ((unsigned)(y0 + 1) < (unsigned)H && (unsigned)(x0 + 1) < (unsigned)W)
            v = fmaf(pl[(y0 + 1) * W + x0 + 1], w11, v);
        s[p][c * 9 + kk] = __float2bfloat16(v);
    }
    __syncthreads();
    if (tid < C) {
        int oc = tid;
        float bz = db[oc];
        float a0 = bz, a1 = bz, a2 = bz, a3 = bz;
#pragma unroll 4
        for (int i = 0; i < 864; ++i) {
            float wv = dwT[i * 96 + oc];                // coalesced across lanes
            a0 = fmaf(b2f(s[0][i]), wv, a0);
            a1 = fmaf(b2f(s[1][i]), wv, a1);
            a2 = fmaf(b2f(s[2][i]), wv, a2);
            a3 = fmaf(b2f(s[3][i]), wv, a3);
        }
        long ob = ((long)b * 16384 + oy * 128 + oxb) * 192 + 96 + oc;
        X2[ob + 0 * 192] = __float2bfloat16(a0);
        X2[ob + 1 * 192] = __float2bfloat16(a1);
        X2[ob + 2 * 192] = __float2bfloat16(a2);
        X2[ob + 3 * 192] = __float2bfloat16(a3);
    }
}

extern "C" void kernel_launch(void* const* d_in, const int* in_sizes, int n_in,
                              void* d_out, int out_size, void* d_ws, size_t ws_size,
                              hipStream_t stream) {
    const float* ref_fea = (const float*)d_in[0];
    const float* inp_fea = (const float*)d_in[1];
    const float* oc1_w = (const float*)d_in[2];  const float* oc1_b = (const float*)d_in[3];
    const float* oc3_w = (const float*)d_in[4];  const float* oc3_b = (const float*)d_in[5];
    const float* enc1_w = (const float*)d_in[6]; const float* enc1_b = (const float*)d_in[7];
    const float* enc2_w = (const float*)d_in[8]; const float* enc2_b = (const float*)d_in[9];
    const float* dec1_w = (const float*)d_in[10]; const float* dec1_b = (const float*)d_in[11];
    const float* dec2_w = (const float*)d_in[12]; const float* dec2_b = (const float*)d_in[13];
    const float* coff_w = (const float*)d_in[14]; const float* coff_b = (const float*)d_in[15];
    const float* dcn_w = (const float*)d_in[16];  const float* dcn_b = (const float*)d_in[17];
    const float* ref1_w = (const float*)d_in[18]; const float* ref1_b = (const float*)d_in[19];
    const float* ref2_w = (const float*)d_in[20]; const float* ref2_b = (const float*)d_in[21];

    float* out = (float*)d_out;
    float* S1 = (float*)d_ws;             // 12.58 MB slot
    float* S2 = S1 + N_FEA;               // 12.58 MB slot
    float* E = S1 + N_E1;                 // en fp32
    float* F = E + N_EN;                  // q fp32
    bf16* de_hwc = (bf16*)S1;             // after F dead
    bf16* offs = (bf16*)S2;               // HWC [b][HW][144], 9.44 MB
    bf16* X2 = (bf16*)S1;                 // [ref | aligned] HWC 192c
    bf16* r1 = (bf16*)S2;                 // 6.29 MB (offs dead)
    bf16* wtb = (bf16*)S2 + 4800000;      // tail at S2+9.6 MB
    bf16* wt_coff = wtb;                  // 124416
    bf16* wt_ref1 = wt_coff + 124416;     // 165888
    bf16* wt_ref2 = wt_ref1 + 165888;     // 82944
    float* dwT = (float*)(wt_ref2 + 82944);  // 864*96 fp32 (331 KB)

    dim3 blk(256);
    auto nb = [](long n) { return dim3((unsigned)((n + 255) / 256)); };

    // ---- encoder (fp32-exact; q must match reference round()) ----
    conv3x3_v2<1, 2><<<dim3(2 * 48 * 16), blk, 0, stream>>>(ref_fea, 96, inp_fea, 96,
                                                            oc1_w, oc1_b, S1, 96, 128, 128, 1);
    conv3x3_v2<1, 2><<<dim3(2 * 48 * 16), blk, 0, stream>>>(S1, 96, S1, 0,
                                                            oc3_w, oc3_b, S2, 96, 128, 128, 1);
    conv3x3_v2<2, 1><<<dim3(2 * 96 * 4), blk, 0, stream>>>(S2, 96, S2, 0,
                                                           enc1_w, enc1_b, S1, 96, 128, 128, 1);
    // S2 tail free from here: weight transforms
    wxform<<<nb(144L * 9 * 96), blk, 0, stream>>>(coff_w, wt_coff, 144, 96, 0);
    wxform<<<nb(96L * 9 * 192), blk, 0, stream>>>(ref1_w, wt_ref1, 96, 192, 1);
    wxform<<<nb(96L * 9 * 96), blk, 0, stream>>>(ref2_w, wt_ref2, 96, 96, 0);
    wxform_dcn<<<nb(864L * 96), blk, 0, stream>>>(dcn_w, dwT);
    conv3x3_v2<2, 1><<<dim3(2 * 96), blk, 0, stream>>>(S1, 96, S1, 0,
                                                       enc2_w, enc2_b, E, 96, 64, 64, 0);
    quant_k<<<nb(N_EN), blk, 0, stream>>>(E, out + OUT_EN, out + OUT_Q, F, N_EN);
    // ---- decoder ----
    convt3x3_v2<0><<<dim3(2 * 96 * 4), blk, 0, stream>>>(F, dec1_w, dec1_b, S2, 32, 32, 1);
    convt3x3_v2<1><<<dim3(2 * 96 * 16), blk, 0, stream>>>(S2, dec2_w, dec2_b, de_hwc,
                                                          64, 64, 0);
    // ---- MFMA: offsets = conv(de) -> HWC bf16 ----
    mconv<0><<<dim3(512), blk, 0, stream>>>(de_hwc, wt_coff, coff_b, offs, nullptr,
                                            96, 144, 128, 128, 0);
    // ---- X2 = [ref | aligned] HWC ----
    pack_hwc<<<nb(N_FEA), blk, 0, stream>>>(ref_fea, X2, 16384, 192, 0);
    deform_lite_k<<<dim3(2 * 128 * 32), dim3(128), 0, stream>>>(ref_fea, offs,
                                                                dwT, dcn_b, X2);
    // ---- MFMA: r1 = lrelu(conv(X2, ref1)); out0 = aligned + lrelu(conv(r1, ref2)) ----
    mconv<0><<<dim3(512), blk, 0, stream>>>(X2, wt_ref1, ref1_b, r1, nullptr,
                                            192, 96, 128, 128, 1);
    mconv<3><<<dim3(512), blk, 0, stream>>>(r1, wt_ref2, ref2_b, out, X2,
                                            96, 96, 128, 128, 1);
}

// Round 9
// 1571.535 us; speedup vs baseline: 3.3506x; 1.0932x over previous
//
#include <hip/hip_runtime.h>
#include <hip/hip_bf16.h>

typedef __hip_bfloat16 bf16;
typedef __attribute__((ext_vector_type(8))) short s8;   // 8 x bf16 MFMA A/B frag
typedef __attribute__((ext_vector_type(4))) float f4;   // MFMA C/D frag

#define N_FEA   3145728   // 2*96*128*128
#define N_EN    196608    // 2*96*32*32
#define N_E1    786432    // 2*96*64*64
#define OUT_EN  3145728
#define OUT_Q   3342336

__device__ __forceinline__ float b2f(bf16 v) { return __bfloat162float(v); }

// ---------------- scalar direct conv (PX=4, OCB oc per block) --------------
// launch_bounds(256,2): allow ~256 VGPR so the compiler can software-pipeline loads.
template <int S, int OCB>
__global__ __launch_bounds__(256, 2) void conv3x3_v2(
    const float* __restrict__ in0, int c0,
    const float* __restrict__ in1, int c1,
    const float* __restrict__ w, const float* __restrict__ bias,
    float* __restrict__ out,
    int Cout, int Hin, int Win, int relu) {
    const int Hout = (Hin - 1) / S + 1, Wout = (Win - 1) / S + 1;
    const int strips = (Hout * Wout) / 1024;
    int bid = blockIdx.x;
    const int strip = bid % strips; bid /= strips;
    const int oc0 = (bid % (Cout / OCB)) * OCB;
    const int b = bid / (Cout / OCB);
    const int Cin = c0 + c1;
    __shared__ float wl[OCB * 1728];
    for (int i = threadIdx.x; i < OCB * Cin * 9; i += 256) {
        int o = i / (Cin * 9), rem = i % (Cin * 9);
        wl[i] = w[(long)(oc0 + o) * Cin * 9 + rem];
    }
    __syncthreads();
    const int pix = strip * 1024 + threadIdx.x * 4;
    const int oy = pix / Wout, oxb = pix % Wout;
    const int iy0 = oy * S - 1, ixb = oxb * S - 1;
    constexpr int NX = 3 * S + 3;
    float acc[OCB][4];
#pragma unroll
    for (int o = 0; o < OCB; ++o) {
        float bz = bias[oc0 + o];
#pragma unroll
        for (int j = 0; j < 4; ++j) acc[o][j] = bz;
    }
    const bool fast = (ixb >= 0) && (ixb + NX - 1 < Win);

    auto seg = [&](const float* base, int nc, int wofs) {
        const float* pl = base + (long)b * nc * Hin * Win;
        for (int c = 0; c < nc; ++c) {
#pragma unroll
            for (int ky = 0; ky < 3; ++ky) {
                int iy = iy0 + ky;
                if ((unsigned)iy >= (unsigned)Hin) continue;
                const float* row = pl + (long)iy * Win + ixb;
                float r[NX];
                if (fast) {
#pragma unroll
                    for (int i = 0; i < NX; ++i) r[i] = row[i];
                } else {
#pragma unroll
                    for (int i = 0; i < NX; ++i) {
                        int col = ixb + i;
                        r[i] = ((unsigned)col < (unsigned)Win) ? row[i] : 0.f;
                    }
                }
#pragma unroll
                for (int o = 0; o < OCB; ++o) {
                    const float* wv = &wl[(o * Cin + wofs + c) * 9 + ky * 3];
#pragma unroll
                    for (int j = 0; j < 4; ++j)
#pragma unroll
                        for (int kx = 0; kx < 3; ++kx)
                            acc[o][j] = fmaf(r[j * S + kx], wv[kx], acc[o][j]);
                }
            }
            pl += (long)Hin * Win;
        }
    };
    seg(in0, c0, 0);
    seg(in1, c1, c0);

#pragma unroll
    for (int o = 0; o < OCB; ++o) {
        long idx = (((long)b * Cout + oc0 + o) * Hout + oy) * Wout + oxb;
#pragma unroll
        for (int j = 0; j < 4; ++j) {
            float a = acc[o][j];
            if (relu) a = a > 0.f ? a : 0.1f * a;
            out[idx + j] = a;
        }
    }
}

// ------------- ConvTranspose2d(96->96,k3,s2,p1,op1), gather, 4 ox/thread --------------
template <int HWC>
__global__ __launch_bounds__(256) void convt3x3_v2(
    const float* __restrict__ in, const float* __restrict__ w,
    const float* __restrict__ bias, void* __restrict__ out,
    int Hin, int Win, int relu) {
    const int C = 96;
    const int Hout = 2 * Hin, Wout = 2 * Win;
    const int strips = (Hout * Wout) / 1024;
    int bid = blockIdx.x;
    const int strip = bid % strips; bid /= strips;
    const int oc = bid % C;
    const int b = bid / C;
    __shared__ float wl[864];
    for (int i = threadIdx.x; i < C * 9; i += 256) {
        int c = i / 9, k = i % 9;
        wl[i] = w[((long)c * C + oc) * 9 + k];
    }
    __syncthreads();
    const int pix = strip * 1024 + threadIdx.x * 4;
    const int oy = pix / Wout, oxb = pix % Wout;
    const int c0x = oxb >> 1;
    const int oyE = oy + 1;
    float acc[4];
    const float bz = bias[oc];
#pragma unroll
    for (int j = 0; j < 4; ++j) acc[j] = bz;
    const bool r2ok = (c0x + 2) < Win;

    const float* pl = in + (long)b * C * Hin * Win;
    for (int c = 0; c < C; ++c) {
        float wv[9];
#pragma unroll
        for (int k = 0; k < 9; ++k) wv[k] = wl[c * 9 + k];
#pragma unroll
        for (int ky = 0; ky < 3; ++ky) {
            int ty = oyE - ky;
            if (ty & 1) continue;
            int iy = ty >> 1;
            if ((unsigned)iy >= (unsigned)Hin) continue;
            const float* row = pl + (long)iy * Win + c0x;
            float r0 = row[0];
            float r1 = row[1];
            float r2 = r2ok ? row[2] : 0.f;
            acc[0] = fmaf(r0, wv[ky * 3 + 1], acc[0]);
            acc[1] = fmaf(r1, wv[ky * 3 + 0], acc[1]);
            acc[1] = fmaf(r0, wv[ky * 3 + 2], acc[1]);
            acc[2] = fmaf(r1, wv[ky * 3 + 1], acc[2]);
            acc[3] = fmaf(r2, wv[ky * 3 + 0], acc[3]);
            acc[3] = fmaf(r1, wv[ky * 3 + 2], acc[3]);
        }
        pl += (long)Hin * Win;
    }
#pragma unroll
    for (int j = 0; j < 4; ++j) {
        float a = acc[j];
        if (relu) a = a > 0.f ? a : 0.1f * a;
        if (HWC)
            ((bf16*)out)[((long)b * Hout * Wout + oy * Wout + oxb + j) * 96 + oc] =
                __float2bfloat16(a);
        else
            ((float*)out)[(((long)b * C + oc) * Hout + oy) * Wout + oxb + j] = a;
    }
}

__global__ void quant_k(const float* __restrict__ en, float* __restrict__ out_en,
                        float* __restrict__ out_q, float* __restrict__ qf, int n) {
    int i = blockIdx.x * 256 + threadIdx.x;
    if (i >= n) return;
    float e = en[i];
    float q = rintf(e);
    out_en[i] = e;
    out_q[i] = q;
    qf[i] = q;
}

// -------- MFMA-B packed weight transform: fp32 [Cout][Cin][3][3] ->
// bf16 [g][tap][ci][lane][8] with lane = q*16+n16, oc = g*16+n16, c = ci*32+q*8+e.
// A wave's B-load becomes 64 consecutive 16B chunks (fully coalesced). --------
__global__ void wxform_pack(const float* __restrict__ w, bf16* __restrict__ wP,
                            int Cout, int Cin, int swap) {
    const int cpt = Cin >> 5;
    long tot = (long)Cout * 9 * Cin;
    long i = (long)blockIdx.x * 256 + threadIdx.x;
    if (i >= tot) return;
    int e = (int)(i & 7);
    int n16 = (int)((i >> 3) & 15);
    int q = (int)((i >> 7) & 3);
    long t = i >> 9;
    int ci = (int)(t % cpt); t /= cpt;
    int tap = (int)(t % 9);
    int g = (int)(t / 9);
    int oc = g * 16 + n16;
    int c = ci * 32 + q * 8 + e;
    int cs = swap ? (c + Cin / 2) % Cin : c;
    wP[i] = __float2bfloat16(w[((long)oc * Cin + cs) * 9 + tap]);
}

// -------- dcn_w fp32 [oc][864] -> fp32 [864][oc] (coalesced per-lane oc reads) --------
__global__ void wxform_dcn(const float* __restrict__ w, float* __restrict__ wT) {
    int i = blockIdx.x * 256 + threadIdx.x;
    if (i >= 864 * 96) return;
    int oc = i % 96, k = i / 96;
    wT[i] = w[(long)oc * 864 + k];
}

// -------- pack fp32 NCHW (96 ch) -> bf16 HWC [b][y][x][Cs] at channel offset --------
__global__ void pack_hwc(const float* __restrict__ src, bf16* __restrict__ dst,
                         int HW, int Cs, int coff) {
    long i = (long)blockIdx.x * 256 + threadIdx.x;
    if (i >= 2L * 96 * HW) return;
    int px = (int)(i % HW);
    long t = i / HW;
    int c = (int)(t % 96);
    int b = (int)(t / 96);
    dst[((long)b * HW + px) * Cs + coff + c] = __float2bfloat16(src[i]);
}

// ----------------- MFMA implicit-GEMM 3x3 conv (stride 1, 128x128) -----------------
// X: bf16 HWC; wP: packed B (see wxform_pack). EPI 0: bf16 HWC out. EPI 3: fp32 NCHW
// + residual from res (192c HWC, channels 96..191).
template <int EPI>
__global__ __launch_bounds__(256) void mconv(
    const bf16* __restrict__ X, const bf16* __restrict__ wP,
    const float* __restrict__ bias, void* __restrict__ out,
    const bf16* __restrict__ res,
    int Cin, int Cout, int H, int W, int relu) {
    const int HW = H * W;
    const int NG = Cout >> 4, split = (NG + 1) >> 1;
    int bid = blockIdx.x;
    const int nb = HW >> 6;
    const int pxb = (bid % nb) << 6;
    const int b = bid / nb;
    const int wave = threadIdx.x >> 6, lane = threadIdx.x & 63;
    const int mt = (wave >> 1) << 5;
    const int og0 = (wave & 1) ? split : 0;
    const int og1 = (wave & 1) ? NG : split;
    const int q = lane >> 4, n16 = lane & 15;
    const int pA0 = pxb + mt + n16, pA1 = pA0 + 16;
    const int oy0 = pA0 / W, ox0 = pA0 % W;
    const int oy1 = pA1 / W, ox1 = pA1 % W;
    const long ib = (long)b * HW * Cin;
    f4 acc0[5], acc1[5];
    const f4 z4 = {0.f, 0.f, 0.f, 0.f};
#pragma unroll
    for (int g = 0; g < 5; ++g) { acc0[g] = z4; acc1[g] = z4; }
    const s8 z8 = {0, 0, 0, 0, 0, 0, 0, 0};
    const int cpt = Cin >> 5;
    const int lofs = lane << 3;                 // lane*8 elems
    for (int tap = 0; tap < 9; ++tap) {
        const int ky = tap / 3 - 1, kx = tap % 3 - 1;
        const int iy0 = oy0 + ky, ix0 = ox0 + kx;
        const int iy1 = oy1 + ky, ix1 = ox1 + kx;
        const bool v0 = (unsigned)iy0 < (unsigned)H && (unsigned)ix0 < (unsigned)W;
        const bool v1 = (unsigned)iy1 < (unsigned)H && (unsigned)ix1 < (unsigned)W;
        const bf16* pa0 = X + ib + ((long)iy0 * W + ix0) * Cin + q * 8;
        const bf16* pa1 = X + ib + ((long)iy1 * W + ix1) * Cin + q * 8;
        for (int ci = 0; ci < cpt; ++ci) {
            const int c0 = ci << 5;
            s8 a0 = v0 ? *(const s8*)(pa0 + c0) : z8;
            s8 a1 = v1 ? *(const s8*)(pa1 + c0) : z8;
#pragma unroll
            for (int gi = 0; gi < 5; ++gi) {
                int g = og0 + gi;
                if (g >= og1) break;
                s8 bb = *(const s8*)(wP + ((long)(g * 9 + tap) * cpt + ci) * 512 + lofs);
                acc0[gi] = __builtin_amdgcn_mfma_f32_16x16x32_bf16(a0, bb, acc0[gi], 0, 0, 0);
                acc1[gi] = __builtin_amdgcn_mfma_f32_16x16x32_bf16(a1, bb, acc1[gi], 0, 0, 0);
            }
        }
    }
#pragma unroll
    for (int gi = 0; gi < 5; ++gi) {
        int g = og0 + gi;
        if (g >= og1) break;
        int oc = g * 16 + n16;
        float bz = bias[oc];
#pragma unroll
        for (int t = 0; t < 2; ++t) {
            f4 a = t ? acc1[gi] : acc0[gi];
            int pxl = pxb + mt + t * 16 + q * 4;
#pragma unroll
            for (int r = 0; r < 4; ++r) {
                float v = a[r] + bz;
                if (relu) v = v > 0.f ? v : 0.1f * v;
                int px = pxl + r;
                if (EPI == 0)
                    ((bf16*)out)[((long)b * HW + px) * Cout + oc] = __float2bfloat16(v);
                else {
                    v += b2f(res[((long)b * HW + px) * 192 + 96 + oc]);
                    ((float*)out)[((long)b * Cout + oc) * HW + px] = v;
                }
            }
        }
    }
}

// -------- DCNv1 sample+contract. offs bf16 HWC [b][HW][144]; dwT fp32 [864][96].
// XCD-banded decode; LDS 9.2 KB; writes aligned into X2 HWC (c 96..191). --------
__global__ __launch_bounds__(128) void deform_lite_k(
    const float* __restrict__ x, const bf16* __restrict__ offs,
    const float* __restrict__ dwT, const float* __restrict__ db,
    bf16* __restrict__ X2) {
    const int H = 128, W = 128, C = 96;
    __shared__ float offL[4][144];
    __shared__ bf16 s[4][864];
    int bid = blockIdx.x;
    int rxcd = bid & 7;
    int i0 = bid >> 3;
    int b = i0 >> 9;
    int rem = i0 & 511;
    int oy = rxcd * 16 + (rem >> 5);
    int oxb = (rem & 31) << 2;
    int tid = threadIdx.x;
    long pxbase = (long)b * (H * W) + oy * W + oxb;
    for (int e = tid; e < 4 * 144; e += 128) {
        int p = e / 144, cc = e % 144;
        offL[p][cc] = b2f(offs[(pxbase + p) * 144 + cc]);
    }
    __syncthreads();
    for (int e = tid; e < 4 * 864; e += 128) {
        int p = e & 3;
        int t = e >> 2;
        int kk = t % 9, c = t / 9, g = c / 12;
        int ox = oxb + p;
        float offy = offL[p][g * 18 + kk * 2];
        float offx = offL[p][g * 18 + kk * 2 + 1];
        float py = (float)(oy + kk / 3 - 1) + offy;
        float px = (float)(ox + kk % 3 - 1) + offx;
        float y0f = floorf(py), x0f = floorf(px);
        float ly = py - y0f, lx = px - x0f;
        int y0 = (int)y0f, x0 = (int)x0f;
        const float* pl = x + ((long)b * C + c) * (long)H * W;
        float w00 = (1.f - ly) * (1.f - lx), w01 = (1.f - ly) * lx;
        float w10 = ly * (1.f - lx), w11 = ly * lx;
        float v = 0.f;
        if ((unsigned)y0 < (unsigned)H && (unsigned)x0 < (unsigned)W)
            v = fmaf(pl[y0 * W + x0], w00, v);
        if ((unsigned)y0 < (unsigned)H && (unsigned)(x0 + 1) < (unsigned)W)
            v = fmaf(pl[y0 * W + x0 + 1], w01, v);
        if ((unsigned)(y0 + 1) < (unsigned)H && (unsigned)x0 < (unsigned)W)
            v = fmaf(pl[(y0 + 1) * W + x0], w10, v);
        if ((unsigned)(y0 + 1) < (unsigned)H && (unsigned)(x0 + 1) < (unsigned)W)
            v = fmaf(pl[(y0 + 1) * W + x0 + 1], w11, v);
        s[p][c * 9 + kk] = __float2bfloat16(v);
    }
    __syncthreads();
    if (tid < C) {
        int oc = tid;
        float bz = db[oc];
        float a0 = bz, a1 = bz, a2 = bz, a3 = bz;
#pragma unroll 4
        for (int i = 0; i < 864; ++i) {
            float wv = dwT[i * 96 + oc];
            a0 = fmaf(b2f(s[0][i]), wv, a0);
            a1 = fmaf(b2f(s[1][i]), wv, a1);
            a2 = fmaf(b2f(s[2][i]), wv, a2);
            a3 = fmaf(b2f(s[3][i]), wv, a3);
        }
        long ob = ((long)b * 16384 + oy * 128 + oxb) * 192 + 96 + oc;
        X2[ob + 0 * 192] = __float2bfloat16(a0);
        X2[ob + 1 * 192] = __float2bfloat16(a1);
        X2[ob + 2 * 192] = __float2bfloat16(a2);
        X2[ob + 3 * 192] = __float2bfloat16(a3);
    }
}

extern "C" void kernel_launch(void* const* d_in, const int* in_sizes, int n_in,
                              void* d_out, int out_size, void* d_ws, size_t ws_size,
                              hipStream_t stream) {
    const float* ref_fea = (const float*)d_in[0];
    const float* inp_fea = (const float*)d_in[1];
    const float* oc1_w = (const float*)d_in[2];  const float* oc1_b = (const float*)d_in[3];
    const float* oc3_w = (const float*)d_in[4];  const float* oc3_b = (const float*)d_in[5];
    const float* enc1_w = (const float*)d_in[6]; const float* enc1_b = (const float*)d_in[7];
    const float* enc2_w = (const float*)d_in[8]; const float* enc2_b = (const float*)d_in[9];
    const float* dec1_w = (const float*)d_in[10]; const float* dec1_b = (const float*)d_in[11];
    const float* dec2_w = (const float*)d_in[12]; const float* dec2_b = (const float*)d_in[13];
    const float* coff_w = (const float*)d_in[14]; const float* coff_b = (const float*)d_in[15];
    const float* dcn_w = (const float*)d_in[16];  const float* dcn_b = (const float*)d_in[17];
    const float* ref1_w = (const float*)d_in[18]; const float* ref1_b = (const float*)d_in[19];
    const float* ref2_w = (const float*)d_in[20]; const float* ref2_b = (const float*)d_in[21];

    float* out = (float*)d_out;
    float* S1 = (float*)d_ws;             // 12.58 MB slot
    float* S2 = S1 + N_FEA;               // 12.58 MB slot
    float* E = S1 + N_E1;                 // en fp32
    float* F = E + N_EN;                  // q fp32
    bf16* de_hwc = (bf16*)S1;             // after F dead
    bf16* offs = (bf16*)S2;               // HWC [b][HW][144], 9.44 MB
    bf16* X2 = (bf16*)S1;                 // [ref | aligned] HWC 192c
    bf16* r1 = (bf16*)S2;                 // 6.29 MB (offs dead)
    bf16* wtb = (bf16*)S2 + 4800000;      // tail at S2+9.6 MB
    bf16* wt_coff = wtb;                  // 124416
    bf16* wt_ref1 = wt_coff + 124416;     // 165888
    bf16* wt_ref2 = wt_ref1 + 165888;     // 82944
    float* dwT = (float*)(wt_ref2 + 82944);  // 864*96 fp32 (331 KB)

    dim3 blk(256);
    auto nb = [](long n) { return dim3((unsigned)((n + 255) / 256)); };

    // ---- encoder (fp32-exact; q must match reference round()) ----
    conv3x3_v2<1, 4><<<dim3(2 * 24 * 16), blk, 0, stream>>>(ref_fea, 96, inp_fea, 96,
                                                            oc1_w, oc1_b, S1, 96, 128, 128, 1);
    conv3x3_v2<1, 4><<<dim3(2 * 24 * 16), blk, 0, stream>>>(S1, 96, S1, 0,
                                                            oc3_w, oc3_b, S2, 96, 128, 128, 1);
    conv3x3_v2<2, 1><<<dim3(2 * 96 * 4), blk, 0, stream>>>(S2, 96, S2, 0,
                                                           enc1_w, enc1_b, S1, 96, 128, 128, 1);
    // S2 tail free from here: weight transforms
    wxform_pack<<<nb(144L * 9 * 96), blk, 0, stream>>>(coff_w, wt_coff, 144, 96, 0);
    wxform_pack<<<nb(96L * 9 * 192), blk, 0, stream>>>(ref1_w, wt_ref1, 96, 192, 1);
    wxform_pack<<<nb(96L * 9 * 96), blk, 0, stream>>>(ref2_w, wt_ref2, 96, 96, 0);
    wxform_dcn<<<nb(864L * 96), blk, 0, stream>>>(dcn_w, dwT);
    conv3x3_v2<2, 1><<<dim3(2 * 96), blk, 0, stream>>>(S1, 96, S1, 0,
                                                       enc2_w, enc2_b, E, 96, 64, 64, 0);
    quant_k<<<nb(N_EN), blk, 0, stream>>>(E, out + OUT_EN, out + OUT_Q, F, N_EN);
    // ---- decoder ----
    convt3x3_v2<0><<<dim3(2 * 96 * 4), blk, 0, stream>>>(F, dec1_w, dec1_b, S2, 32, 32, 1);
    convt3x3_v2<1><<<dim3(2 * 96 * 16), blk, 0, stream>>>(S2, dec2_w, dec2_b, de_hwc,
                                                          64, 64, 0);
    // ---- MFMA: offsets = conv(de) -> HWC bf16 ----
    mconv<0><<<dim3(512), blk, 0, stream>>>(de_hwc, wt_coff, coff_b, offs, nullptr,
                                            96, 144, 128, 128, 0);
    // ---- X2 = [ref | aligned] HWC ----
    pack_hwc<<<nb(N_FEA), blk, 0, stream>>>(ref_fea, X2, 16384, 192, 0);
    deform_lite_k<<<dim3(2 * 128 * 32), dim3(128), 0, stream>>>(ref_fea, offs,
                                                                dwT, dcn_b, X2);
    // ---- MFMA: r1 = lrelu(conv(X2, ref1)); out0 = aligned + lrelu(conv(r1, ref2)) ----
    mconv<0><<<dim3(512), blk, 0, stream>>>(X2, wt_ref1, ref1_b, r1, nullptr,
                                            192, 96, 128, 128, 1);
    mconv<3><<<dim3(512), blk, 0, stream>>>(r1, wt_ref2, ref2_b, out, X2,
                                            96, 96, 128, 128, 1);
}